// Round 5
// baseline (115.019 us; speedup 1.0000x reference)
//
#include <hip/hip_runtime.h>

#define NN 32767   // n_nodes
#define NL 16384   // n_leaves
#define DD 1024    // D
#define LL 32      // num labels

typedef __attribute__((ext_vector_type(8))) short bf16x8;
typedef __attribute__((ext_vector_type(4))) float f32x4;

#define MFMA __builtin_amdgcn_mfma_f32_16x16x32_bf16

__device__ __forceinline__ short f2bf(float f) {
  union { float f; unsigned u; } x; x.f = f;
  unsigned r = x.u + 0x7FFFu + ((x.u >> 16) & 1u);  // RNE
  return (short)(r >> 16);
}

__device__ __forceinline__ bf16x8 cvt8(float4 a, float4 b) {
  bf16x8 r;
  r[0] = f2bf(a.x); r[1] = f2bf(a.y); r[2] = f2bf(a.z); r[3] = f2bf(a.w);
  r[4] = f2bf(b.x); r[5] = f2bf(b.y); r[6] = f2bf(b.z); r[7] = f2bf(b.w);
  return r;
}

__device__ __forceinline__ void gld_lds16(const float* g, float* l) {
  __builtin_amdgcn_global_load_lds(
      (const __attribute__((address_space(1))) void*)g,
      (__attribute__((address_space(3))) void*)l, 16, 0, 0);
}

// Pack W_pred into bf16 MFMA B-fragment granules: granule s (=K/32 step,
// s=0..31) occupies shorts [s*2048, (s+1)*2048): unit idx = lane*4 + m,
// 8 shorts each. m: 0=W1c0-15, 1=W1c16-31, 2=W2c0-15, 3=W2c16-31.
__global__ __launch_bounds__(256) void pack_kernel(const float* __restrict__ Wp,
                                                   short* __restrict__ Wpk) {
  int idx = blockIdx.x * 256 + threadIdx.x;   // grid 64 -> 16384 threads
  #pragma unroll
  for (int t = 0; t < 4; ++t, idx += 16384) {
    const int j = idx & 7, m = (idx >> 3) & 3, lane = (idx >> 5) & 63, s = idx >> 11;
    const int wrow = (lane & 15) + 16 * (m & 1);
    const int wcol = (m >> 1) * 1024 + s * 32 + (lane >> 4) * 8 + j;
    Wpk[idx] = f2bf(Wp[(size_t)wrow * (2 * DD) + wcol]);
  }
}

// E0 = hidden @ W1^T (stored) + per-block rowsum partial of E2 = hidden@W2^T.
// Block: 64 rows, 4 waves (16 rows each). Per K-chunk (64 cols): stage A
// (16KB, XOR-swizzled via global source) + W (8KB, [gran][m][lane]) with 6
// global_load_lds/thread, double-buffered, counted vmcnt(6), 2 barriers.
__global__ __launch_bounds__(256, 2) void gemm_kernel(
    const float* __restrict__ hidden, const short* __restrict__ Wpk,
    float* __restrict__ E0, float* __restrict__ gpartB) {
  __shared__ float Abuf[2][4096];   // 2 x 16KB: [row 0..63][unit 0..15] f32x4
  __shared__ float Wbuf[2][2048];   // 2 x 8KB:  [gran][m][lane] 16B units
  __shared__ float part2[4][LL];

  const int tid = threadIdx.x;
  const int w = tid >> 6, lane = tid & 63;
  const int mrow = lane & 15, g = lane >> 4;
  const int b = blockIdx.x;

  // --- staging source pointers (per thread) ---
  const float* pA0; const float* pA1; const float* pA2; const float* pA3;
  #define MKA(R_, P_) { const int U = (R_)*256 + tid;                        \
    const int lr = U >> 4, u = U & 15;                                       \
    int grow = b * 64 + lr; if (grow > NN - 1) grow = NN - 1;                \
    P_ = hidden + (size_t)grow * DD + ((u ^ (lr & 7)) << 2); }
  MKA(0, pA0) MKA(1, pA1) MKA(2, pA2) MKA(3, pA3)
  #undef MKA
  const short* pW = Wpk + lane * 32 + w * 8;

  // uniform (per-wave) LDS dest offsets, in floats
  const int aoff0 = 0 * 1024 + w * 256;
  const int aoff1 = 1 * 1024 + w * 256;
  const int aoff2 = 2 * 1024 + w * 256;
  const int aoff3 = 3 * 1024 + w * 256;
  const int woff0 = w * 256;
  const int woff1 = 1024 + w * 256;

  // consume-side constants
  const int r7 = mrow & 7;
  const int rowb = (w * 16 + mrow) * 64;     // floats
  const int lane4 = lane * 4;                // floats
  const int au00 = ((2 * g) ^ r7) << 2;
  const int au01 = ((2 * g + 1) ^ r7) << 2;
  const int au10 = ((8 + 2 * g) ^ r7) << 2;
  const int au11 = ((9 + 2 * g) ^ r7) << 2;

  f32x4 acc0 = {0,0,0,0}, acc1 = {0,0,0,0}, acc2 = {0,0,0,0}, acc3 = {0,0,0,0};

#define STAGE(KC) {                                                          \
    float* ab_ = Abuf[(KC) & 1];                                             \
    gld_lds16(pA0 + (KC) * 64, ab_ + aoff0);                                 \
    gld_lds16(pA1 + (KC) * 64, ab_ + aoff1);                                 \
    gld_lds16(pA2 + (KC) * 64, ab_ + aoff2);                                 \
    gld_lds16(pA3 + (KC) * 64, ab_ + aoff3);                                 \
    float* wb_ = Wbuf[(KC) & 1];                                             \
    gld_lds16((const float*)(pW + (size_t)(KC) * 4096),        wb_ + woff0); \
    gld_lds16((const float*)(pW + (size_t)(KC) * 4096 + 2048), wb_ + woff1); }

#define COMPUTE(KC) {                                                        \
    const float* ab_ = Abuf[(KC) & 1] + rowb;                                \
    const float* wb_ = Wbuf[(KC) & 1];                                       \
    float4 a0 = *(const float4*)(ab_ + au00);                                \
    float4 a1 = *(const float4*)(ab_ + au01);                                \
    bf16x8 af0 = cvt8(a0, a1);                                               \
    bf16x8 w0 = *(const bf16x8*)(wb_ + lane4);                               \
    bf16x8 w1 = *(const bf16x8*)(wb_ + 256 + lane4);                         \
    bf16x8 w2 = *(const bf16x8*)(wb_ + 512 + lane4);                         \
    bf16x8 w3 = *(const bf16x8*)(wb_ + 768 + lane4);                         \
    acc0 = MFMA(af0, w0, acc0, 0,0,0);                                       \
    acc1 = MFMA(af0, w1, acc1, 0,0,0);                                       \
    acc2 = MFMA(af0, w2, acc2, 0,0,0);                                       \
    acc3 = MFMA(af0, w3, acc3, 0,0,0);                                       \
    float4 a2 = *(const float4*)(ab_ + au10);                                \
    float4 a3 = *(const float4*)(ab_ + au11);                                \
    bf16x8 af1 = cvt8(a2, a3);                                               \
    bf16x8 x0 = *(const bf16x8*)(wb_ + 1024 + lane4);                        \
    bf16x8 x1 = *(const bf16x8*)(wb_ + 1280 + lane4);                        \
    bf16x8 x2 = *(const bf16x8*)(wb_ + 1536 + lane4);                        \
    bf16x8 x3 = *(const bf16x8*)(wb_ + 1792 + lane4);                        \
    acc0 = MFMA(af1, x0, acc0, 0,0,0);                                       \
    acc1 = MFMA(af1, x1, acc1, 0,0,0);                                       \
    acc2 = MFMA(af1, x2, acc2, 0,0,0);                                       \
    acc3 = MFMA(af1, x3, acc3, 0,0,0); }

#define CHUNK(KC) {                                                          \
    STAGE(KC + 1)                                                            \
    asm volatile("s_waitcnt vmcnt(6)" ::: "memory");                         \
    __builtin_amdgcn_s_barrier();                                            \
    COMPUTE(KC)                                                              \
    __builtin_amdgcn_s_barrier(); }

  STAGE(0)
  CHUNK(0)  CHUNK(1)  CHUNK(2)  CHUNK(3)
  CHUNK(4)  CHUNK(5)  CHUNK(6)  CHUNK(7)
  CHUNK(8)  CHUNK(9)  CHUNK(10) CHUNK(11)
  CHUNK(12) CHUNK(13) CHUNK(14)
  // last chunk: nothing left to stage
  asm volatile("s_waitcnt vmcnt(0)" ::: "memory");
  __builtin_amdgcn_s_barrier();
  COMPUTE(15)
#undef CHUNK
#undef COMPUTE
#undef STAGE

  // E0 store: D layout col=lane&15, row=(lane>>4)*4+r
  #pragma unroll
  for (int r = 0; r < 4; ++r) {
    const int srow = b * 64 + w * 16 + g * 4 + r;
    if (srow < NN) {
      E0[(size_t)srow * LL + mrow]      = acc0[r];
      E0[(size_t)srow * LL + mrow + 16] = acc1[r];
    }
  }
  // E2 rowsum partial (drop duplicated clamped row 32767->32766)
  const int tile = b * 4 + w;
  if (tile == 2047 && g == 3) { acc2[3] = 0.f; acc3[3] = 0.f; }
  float s2 = acc2[0] + acc2[1] + acc2[2] + acc2[3];
  float s3 = acc3[0] + acc3[1] + acc3[2] + acc3[3];
  s2 += __shfl_xor(s2, 16, 64); s2 += __shfl_xor(s2, 32, 64);
  s3 += __shfl_xor(s3, 16, 64); s3 += __shfl_xor(s3, 32, 64);
  if (lane < 32) part2[w][lane] = (lane < 16) ? s2 : s3;
  __syncthreads();
  if (tid < LL) {
    float s = part2[0][tid] + part2[1][tid] + part2[2][tid] + part2[3][tid];
    gpartB[b * LL + tid] = s;
  }
}

__device__ __forceinline__ float lse32(const float4* tt, const float4* sv) {
  float m = -3.0e38f;
  float4 v[8];
  #pragma unroll
  for (int i = 0; i < 8; ++i) {
    float4 t = tt[i], s = sv[i], w;
    w.x = t.x + s.x; w.y = t.y + s.y; w.z = t.z + s.z; w.w = t.w + s.w;
    v[i] = w;
    m = fmaxf(m, fmaxf(fmaxf(w.x, w.y), fmaxf(w.z, w.w)));
  }
  float ss = 0.f;
  #pragma unroll
  for (int i = 0; i < 8; ++i) {
    ss += __expf(v[i].x - m) + __expf(v[i].y - m) +
          __expf(v[i].z - m) + __expf(v[i].w - m);
  }
  return m + __logf(ss);
}

// In-block cvec: cv[j] = b[j] + colsum(gpartB)/NN  (gpartB: 512x32)
__device__ __forceinline__ void compute_cvec(const float* __restrict__ gpartB,
                                             const float* __restrict__ bp,
                                             float* cv, float (*pr)[LL]) {
  const int tid = threadIdx.x;
  const int j = tid & 31, r = tid >> 5;   // needs 1024 threads
  float s = 0.f;
  #pragma unroll
  for (int q = 0; q < 16; ++q) s += gpartB[(size_t)(r + q * 32) * LL + j];
  pr[r][j] = s;
  __syncthreads();
  if (tid < LL) {
    float ss = 0.f;
    #pragma unroll
    for (int q = 0; q < 32; ++q) ss += pr[q][tid];
    cv[tid] = bp[tid] + ss * (1.0f / (float)NN);
  }
  __syncthreads();
}

// Five tree levels (widths 8192..512). Children of base_l+n: base_{l-1}+2n,+1.
__global__ __launch_bounds__(1024) void tree_kernel(
    const float* __restrict__ E0, const float* __restrict__ gpartB,
    const float* __restrict__ bp, const float* __restrict__ trans,
    float* __restrict__ dst) {
  __shared__ __align__(16) float cv[LL];
  __shared__ float pr[32][LL];
  __shared__ float l1[16][LL], l2[8][LL], l3[4][LL];
  compute_cvec(gpartB, bp, cv, pr);

  const int wid = threadIdx.x >> 6, lane = threadIdx.x & 63;
  const int j = lane & 31, half = lane >> 5;
  const int b = blockIdx.x, G = gridDim.x;
  float4 tt[8];
  #pragma unroll
  for (int i = 0; i < 8; ++i) tt[i] = *(const float4*)(trans + j * LL + i * 4);
  const float cj = cv[j];
  float4 sv[8];
  const int base1 = NL;

  { // phase 1 (leaves as children)
    const int n = b * 16 + wid;
    const float* sp = E0 + (size_t)(2 * n + half) * LL;
    #pragma unroll
    for (int i = 0; i < 8; ++i) {
      float4 vv = *(const float4*)(sp + i * 4);
      float4 c4 = *(const float4*)(cv + i * 4);
      vv.x += c4.x; vv.y += c4.y; vv.z += c4.z; vv.w += c4.w;
      sv[i] = vv;
    }
    float lsum = lse32(tt, sv);
    float other = __shfl_xor(lsum, 32, 64);
    float o = E0[(size_t)(base1 + n) * LL + j] + cj + lsum + other;
    if (lane < 32) l1[wid][j] = o;
  }
  __syncthreads();
  const int base2 = base1 + G * 16;
  if (wid < 8) {
    const float* sp = l1[2 * wid + half];
    #pragma unroll
    for (int i = 0; i < 8; ++i) sv[i] = *(const float4*)(sp + i * 4);
    float lsum = lse32(tt, sv);
    float other = __shfl_xor(lsum, 32, 64);
    float o = E0[(size_t)(base2 + b * 8 + wid) * LL + j] + cj + lsum + other;
    if (lane < 32) l2[wid][j] = o;
  }
  __syncthreads();
  const int base3 = base2 + G * 8;
  if (wid < 4) {
    const float* sp = l2[2 * wid + half];
    #pragma unroll
    for (int i = 0; i < 8; ++i) sv[i] = *(const float4*)(sp + i * 4);
    float lsum = lse32(tt, sv);
    float other = __shfl_xor(lsum, 32, 64);
    float o = E0[(size_t)(base3 + b * 4 + wid) * LL + j] + cj + lsum + other;
    if (lane < 32) l3[wid][j] = o;
  }
  __syncthreads();
  const int base4 = base3 + G * 4;
  if (wid < 2) {
    const float* sp = l3[2 * wid + half];
    #pragma unroll
    for (int i = 0; i < 8; ++i) sv[i] = *(const float4*)(sp + i * 4);
    float lsum = lse32(tt, sv);
    float other = __shfl_xor(lsum, 32, 64);
    float o = E0[(size_t)(base4 + b * 2 + wid) * LL + j] + cj + lsum + other;
    if (lane < 32) l1[wid][j] = o;
  }
  __syncthreads();
  const int base5 = base4 + G * 2;
  if (wid == 0) {
    const float* sp = l1[half];
    #pragma unroll
    for (int i = 0; i < 8; ++i) sv[i] = *(const float4*)(sp + i * 4);
    float lsum = lse32(tt, sv);
    float other = __shfl_xor(lsum, 32, 64);
    float o = E0[(size_t)(base5 + b) * LL + j] + cj + lsum + other;
    if (lane < 32) dst[(size_t)b * LL + j] = o;
  }
}

// Widths 256..1 in one block (nodes 32256..32766); children of first level
// come from S5 (nodes 31744..32255). Writes root scores to out.
__global__ __launch_bounds__(1024) void tail_kernel(
    const float* __restrict__ E0, const float* __restrict__ gpartB,
    const float* __restrict__ bp, const float* __restrict__ trans,
    const float* __restrict__ S5, float* __restrict__ out) {
  __shared__ __align__(16) float cv[LL];
  __shared__ float pr[32][LL];
  __shared__ float ts[511 * LL];    // nodes 32256..32766
  compute_cvec(gpartB, bp, cv, pr);

  const int wid = threadIdx.x >> 6, lane = threadIdx.x & 63;
  const int j = lane & 31, half = lane >> 5;
  float4 tt[8];
  #pragma unroll
  for (int i = 0; i < 8; ++i) tt[i] = *(const float4*)(trans + j * LL + i * 4);
  const float cj = cv[j];
  float4 sv[8];

  int width = 256, pnode = 32256, cIdxBase = -1;
  while (width >= 1) {
    for (int n = wid; n < width; n += 16) {
      const float* sp = (cIdxBase < 0)
          ? (S5 + (size_t)(2 * n + half) * LL)
          : (ts + (size_t)(cIdxBase + 2 * n + half) * LL);
      #pragma unroll
      for (int i = 0; i < 8; ++i) sv[i] = *(const float4*)(sp + i * 4);
      float lsum = lse32(tt, sv);
      float other = __shfl_xor(lsum, 32, 64);
      if (lane < 32) {
        const int node = pnode + n;
        float o = E0[(size_t)node * LL + j] + cj + lsum + other;
        ts[(size_t)(node - 32256) * LL + j] = o;
        if (node == NN - 1) out[j] = o;
      }
    }
    __syncthreads();
    cIdxBase = pnode - 32256;
    pnode += width;
    width >>= 1;
  }
}

extern "C" void kernel_launch(void* const* d_in, const int* in_sizes, int n_in,
                              void* d_out, int out_size, void* d_ws, size_t ws_size,
                              hipStream_t stream) {
  const float* hidden = (const float*)d_in[0];
  const float* trans  = (const float*)d_in[1];
  const float* Wp     = (const float*)d_in[2];
  const float* bp     = (const float*)d_in[3];

  float* ws     = (float*)d_ws;
  float* E0     = ws;                               // NN*32 f32
  float* gpartB = E0 + (size_t)NN * LL;             // 512*32 f32
  float* S5     = gpartB + 512 * LL;                // 512*32 f32
  short* Wpk    = (short*)(S5 + 512 * LL);          // 65536 bf16

  pack_kernel<<<64, 256, 0, stream>>>(Wp, Wpk);
  gemm_kernel<<<512, 256, 0, stream>>>(hidden, Wpk, E0, gpartB);
  // widths 8192..512 -> S5 = nodes 31744..32255
  tree_kernel<<<512, 1024, 0, stream>>>(E0, gpartB, bp, trans, S5);
  // widths 256..1 + root write
  tail_kernel<<<1, 1024, 0, stream>>>(E0, gpartB, bp, trans, S5, (float*)d_out);
}